// Round 13
// baseline (460.930 us; speedup 1.0000x reference)
//
#include <hip/hip_runtime.h>
#include <hip/hip_bf16.h>

// B=64, D=1024, M=1024, DMODEL=1024, PRED_LEN=96
//   hp[b,i,f] = sum_c h[b,i,c]*pw[f,c] + pb[f]
//   P [b,i,f] = sum_m u[i,m]*lam[b,f,m]
//   diag[b,i] = sum_f hp[b,i,f]*P[b,i,f];  out[b,i,:] = diag[b,i] + bias[i]
//
// cvt2(h,lam f32->bf16) -> ONE fused kernel per (b,i-tile,f-tile):
// hp-tile GEMM -> pack bf16+pb in regs -> P-tile GEMM -> in-register
// hadamard/rowsum -> 16 partial strips -> fast strip-sum broadcast.
// GEMM core: single-barrier-per-K-step pipeline; frag reads feed MFMA with
// compiler-scheduled partial lgkmcnt (no forced drain before MFMA); stage of
// tile t+2 at phase tail after lgkm0+barrier; counted vmcnt(8), never 0 in
// steady state.

#define D_    1024
#define BATCH 64
#define PRED  96

typedef __attribute__((ext_vector_type(8))) short  bf16x8;
typedef __attribute__((ext_vector_type(8))) ushort ushort8;
typedef __attribute__((ext_vector_type(4))) float  f32x4;
typedef __attribute__((ext_vector_type(4))) ushort us4;

__device__ __forceinline__ ushort f2bf(float f){
  union { __hip_bfloat16 b; ushort u; } cv;
  cv.b = __float2bfloat16(f);
  return cv.u;
}
__device__ __forceinline__ float bf2f(ushort v){
  union { ushort u; __hip_bfloat16 b; } cv;
  cv.u = v;
  return __bfloat162float(cv.b);
}

// bijective XCD swizzle (m204 form)
__device__ __forceinline__ int xcd_swz(int orig, int nwg){
  int q = nwg >> 3, r = nwg & 7;
  int x = orig & 7, o = orig >> 3;
  return (x < r ? x*(q+1) : r*(q+1) + (x-r)*q) + o;
}

// async global->LDS, 16B per lane; LDS dest = wave-uniform base + lane*16
__device__ __forceinline__ void gload16(const ushort* g, ushort* l){
  __builtin_amdgcn_global_load_lds(
      (const __attribute__((address_space(1))) void*)g,
      (__attribute__((address_space(3))) void*)l, 16, 0, 0);
}

// ------- tiny f32 -> bf16 convert (u/pw) -------
__global__ __launch_bounds__(256) void cvt_bf16(const float* __restrict__ in,
                                                ushort* __restrict__ out, int n4){
  int stride = (int)gridDim.x * 256;
  for (int i = (int)blockIdx.x*256 + (int)threadIdx.x; i < n4; i += stride){
    f32x4 a = __builtin_nontemporal_load((const f32x4*)in + i);
    us4 o;
    o.x = f2bf(a.x); o.y = f2bf(a.y); o.z = f2bf(a.z); o.w = f2bf(a.w);
    *(us4*)(out + (size_t)i*4) = o;
  }
}

// ------- big f32 -> bf16 convert, h and lam in one pass -------
// nt loads (f32 never re-read); REGULAR stores (bf16 reused by GEMM -> L3).
__global__ __launch_bounds__(256) void cvt2_bf16(
    const float* __restrict__ inA, ushort* __restrict__ outA,
    const float* __restrict__ inB, ushort* __restrict__ outB, int n8each){
  int stride = (int)gridDim.x * 256;
  for (int i = (int)blockIdx.x*256 + (int)threadIdx.x; i < 2*n8each; i += stride){
    const f32x4* src; ushort* dst; int j;
    if (i < n8each){ src = (const f32x4*)inA; dst = outA; j = i; }
    else           { src = (const f32x4*)inB; dst = outB; j = i - n8each; }
    f32x4 a = __builtin_nontemporal_load(src + 2*(size_t)j);
    f32x4 b = __builtin_nontemporal_load(src + 2*(size_t)j + 1);
    ushort8 o;
    o[0]=f2bf(a.x); o[1]=f2bf(a.y); o[2]=f2bf(a.z); o[3]=f2bf(a.w);
    o[4]=f2bf(b.x); o[5]=f2bf(b.y); o[6]=f2bf(b.z); o[7]=f2bf(b.w);
    *(ushort8*)(dst + (size_t)j*8) = o;
  }
}

// K-loop core: depth-2 counted pipeline, ONE barrier per K-step.
// Phase t: frag-read buf[t&1] -> MFMA (compiler-scheduled lgkm waits) ->
// lgkm0 -> barrier -> stage tile t+2 into buf[t&1] -> vmcnt(8).
// T2: LDS[r][chunk] = G[r][chunk ^ (r&7)] via pre-swizzled source.
#define GEMM_CORE(Apan, Bpan, ACC)                                              \
  {                                                                             \
    _Pragma("unroll")                                                           \
    for (int q = 0; q < 4; ++q){                                                \
      int r0 = q*32 + wv*8;                                                     \
      gload16(Apan + (size_t)(r0 + srow)*D_ + scol, sA + r0*64);                \
      gload16(Bpan + (size_t)(r0 + srow)*D_ + scol, sB + r0*64);                \
    }                                                                           \
    _Pragma("unroll")                                                           \
    for (int q = 0; q < 4; ++q){                                                \
      int r0 = q*32 + wv*8;                                                     \
      gload16(Apan + 64 + (size_t)(r0 + srow)*D_ + scol, sA + 128*64 + r0*64);  \
      gload16(Bpan + 64 + (size_t)(r0 + srow)*D_ + scol, sB + 128*64 + r0*64);  \
    }                                                                           \
    asm volatile("s_waitcnt vmcnt(8)" ::: "memory");                            \
    __builtin_amdgcn_s_barrier();                                               \
    for (int t = 0; t < 16; ++t){                                               \
      const int cur = t & 1;                                                    \
      ushort* sAc = sA + cur*(128*64);                                          \
      ushort* sBc = sB + cur*(128*64);                                          \
      bf16x8 af[2][4], bfr[2][4];                                               \
      _Pragma("unroll")                                                         \
      for (int kk = 0; kk < 2; ++kk){                                           \
        int cb = kk*4 + (lane >> 4);                                            \
        _Pragma("unroll")                                                       \
        for (int x = 0; x < 4; ++x){                                            \
          int ra = wr*64 + x*16 + (lane & 15);                                  \
          af[kk][x]  = *(const bf16x8*)(sAc + ra*64 + ((cb ^ (ra & 7)) << 3));  \
          int rb = wc*64 + x*16 + (lane & 15);                                  \
          bfr[kk][x] = *(const bf16x8*)(sBc + rb*64 + ((cb ^ (rb & 7)) << 3));  \
        }                                                                       \
      }                                                                         \
      __builtin_amdgcn_s_setprio(1);                                            \
      _Pragma("unroll")                                                         \
      for (int kk = 0; kk < 2; ++kk)                                            \
        _Pragma("unroll")                                                       \
        for (int x = 0; x < 4; ++x)                                             \
          _Pragma("unroll")                                                     \
          for (int y = 0; y < 4; ++y)                                           \
            ACC[x][y] = __builtin_amdgcn_mfma_f32_16x16x32_bf16(                \
                            af[kk][x], bfr[kk][y], ACC[x][y], 0, 0, 0);         \
      __builtin_amdgcn_s_setprio(0);                                            \
      asm volatile("s_waitcnt lgkmcnt(0)" ::: "memory");                        \
      __builtin_amdgcn_s_barrier();                                             \
      if (t < 14){                                                              \
        const ushort* An = Apan + (t+2)*64;                                     \
        const ushort* Bn = Bpan + (t+2)*64;                                     \
        _Pragma("unroll")                                                       \
        for (int q = 0; q < 4; ++q){                                            \
          int r0 = q*32 + wv*8;                                                 \
          gload16(An + (size_t)(r0 + srow)*D_ + scol, sAc + r0*64);             \
          gload16(Bn + (size_t)(r0 + srow)*D_ + scol, sBc + r0*64);             \
        }                                                                       \
        asm volatile("s_waitcnt vmcnt(8)" ::: "memory");                        \
      } else if (t == 14){                                                      \
        asm volatile("s_waitcnt vmcnt(0)" ::: "memory");                        \
      }                                                                         \
    }                                                                           \
  }

// ---------------- fused: hp-tile GEMM + P-tile GEMM + diag epilogue ----------------
__global__ __launch_bounds__(256, 2) void fused_diag(
    const ushort* __restrict__ hbf, const ushort* __restrict__ pwbf,
    const ushort* __restrict__ ubf, const ushort* __restrict__ lambf,
    const float* __restrict__ pb, float* __restrict__ partial, int b0)
{
  __shared__ ushort sA[2*128*64];
  __shared__ ushort sB[2*128*64];
  int bid = xcd_swz((int)blockIdx.x, (int)gridDim.x);
  int bl = bid >> 6;
  int t_ = bid & 63;
  int it = t_ >> 3, ft = t_ & 7;
  const ushort* ApanH = hbf  + ((size_t)bl << 20) + (size_t)(it*128) * D_;
  const ushort* BpanW = pwbf + (size_t)(ft*128) * D_;
  const ushort* ApanU = ubf  + (size_t)(it*128) * D_;
  const ushort* BpanL = lambf + ((size_t)bl << 20) + (size_t)(ft*128) * D_;
  int tid = threadIdx.x, lane = tid & 63, wv = tid >> 6;
  int wr = wv >> 1, wc = wv & 1;
  int srow = lane >> 3;
  int scol = (((lane & 7) ^ srow) << 3);     // T2 pre-swizzled source chunk

  f32x4 acc[4][4];
  #pragma unroll
  for (int x = 0; x < 4; ++x)
    #pragma unroll
    for (int y = 0; y < 4; ++y) acc[x][y] = (f32x4){0.f,0.f,0.f,0.f};

  // ---- loop 1: hp-tile = h @ pw^T ----
  GEMM_CORE(ApanH, BpanW, acc)

  // pack hp (+pb) to bf16 in registers; reset acc for loop 2
  us4 hp_pk[4][4];
  #pragma unroll
  for (int y = 0; y < 4; ++y){
    int gk = ft*128 + wc*64 + y*16 + (lane & 15);
    float pbv = pb[gk];
    #pragma unroll
    for (int x = 0; x < 4; ++x){
      us4 p;
      p.x = f2bf(acc[x][y][0] + pbv); p.y = f2bf(acc[x][y][1] + pbv);
      p.z = f2bf(acc[x][y][2] + pbv); p.w = f2bf(acc[x][y][3] + pbv);
      hp_pk[x][y] = p;
      acc[x][y] = (f32x4){0.f,0.f,0.f,0.f};
    }
  }

  // ---- loop 2: P-tile = u @ lam^T ----
  GEMM_CORE(ApanU, BpanL, acc)

  // ---- epilogue: ps = rowsum over this wave's 64 cols of hp .* P ----
  f32x4 ps[4];
  #pragma unroll
  for (int x = 0; x < 4; ++x) ps[x] = (f32x4){0.f,0.f,0.f,0.f};
  #pragma unroll
  for (int y = 0; y < 4; ++y)
    #pragma unroll
    for (int x = 0; x < 4; ++x){
      ps[x][0] += bf2f(hp_pk[x][y].x) * acc[x][y][0];
      ps[x][1] += bf2f(hp_pk[x][y].y) * acc[x][y][1];
      ps[x][2] += bf2f(hp_pk[x][y].z) * acc[x][y][2];
      ps[x][3] += bf2f(hp_pk[x][y].w) * acc[x][y][3];
    }
  // butterfly over the 16 cols (lane bits 0..3); preserves row group (lane>>4)
  #pragma unroll
  for (int x = 0; x < 4; ++x)
    #pragma unroll
    for (int r = 0; r < 4; ++r){
      float v = ps[x][r];
      #pragma unroll
      for (int mm = 1; mm < 16; mm <<= 1) v += __shfl_xor(v, mm, 64);
      ps[x][r] = v;
    }
  // deterministic partial strips: strip = ft*2 + wc  (16 strips)
  if ((lane & 15) == 0){
    int strip = ft*2 + wc;
    float* pdst = partial + (size_t)strip*(BATCH*D_) + (size_t)(b0 + bl)*D_;
    #pragma unroll
    for (int x = 0; x < 4; ++x){
      int gi0 = it*128 + wr*64 + x*16 + (lane >> 4)*4;
      #pragma unroll
      for (int r = 0; r < 4; ++r) pdst[gi0 + r] = ps[x][r];
    }
  }
}

// ------- K3: diag = sum(strips) + bias; broadcast to 96 (fast 512-block) -------
__global__ __launch_bounds__(256) void bcast_out(
    const float* __restrict__ partial, const float* __restrict__ bias,
    float* __restrict__ out)
{
  int tid = threadIdx.x;
  int row = (int)blockIdx.x*128 + (tid >> 1);   // 512 blocks x 128 rows
  int half = tid & 1;
  int i = row & (D_-1);
  float s = bias[i];
  #pragma unroll
  for (int st = 0; st < 16; ++st) s += partial[(size_t)st*(BATCH*D_) + row];
  f32x4 v = {s, s, s, s};
  float* dst = out + (size_t)row*PRED + half*48;
  #pragma unroll
  for (int j = 0; j < 12; ++j) ((f32x4*)dst)[j] = v;
}

// ---------------- emergency path: no workspace needed (slow, correct) ----------------
__global__ __launch_bounds__(256) void emergency_fused(
    const float* __restrict__ h, const float* __restrict__ lam,
    const float* __restrict__ uu, const float* __restrict__ bias,
    const float* __restrict__ pw, const float* __restrict__ pb,
    float* __restrict__ out)
{
  int b = blockIdx.x >> 10;
  int i = blockIdx.x & (D_-1);
  __shared__ float hps[D_];
  __shared__ float red[4];
  __shared__ float dv;
  const float* hrow = h + ((size_t)b << 20) + (size_t)i*D_;
  for (int f = threadIdx.x; f < D_; f += 256){
    const float* pwr = pw + (size_t)f*D_;
    float s = pb[f];
    for (int c = 0; c < D_; ++c) s += hrow[c]*pwr[c];
    hps[f] = s;
  }
  __syncthreads();
  const float* urow = uu + (size_t)i*D_;
  float d = 0.f;
  for (int f = threadIdx.x; f < D_; f += 256){
    const float* lr = lam + ((size_t)b << 20) + (size_t)f*D_;
    float p = 0.f;
    for (int m = 0; m < D_; ++m) p += lr[m]*urow[m];
    d += hps[f]*p;
  }
  for (int off = 32; off; off >>= 1) d += __shfl_down(d, off, 64);
  if ((threadIdx.x & 63) == 0) red[threadIdx.x >> 6] = d;
  __syncthreads();
  if (threadIdx.x == 0) dv = red[0]+red[1]+red[2]+red[3] + bias[i];
  __syncthreads();
  if (threadIdx.x < PRED) out[(size_t)blockIdx.x*PRED + threadIdx.x] = dv;
}

extern "C" void kernel_launch(void* const* d_in, const int* in_sizes, int n_in,
                              void* d_out, int out_size, void* d_ws, size_t ws_size,
                              hipStream_t stream) {
  const float* h    = (const float*)d_in[0];
  const float* lam  = (const float*)d_in[1];
  const float* uu   = (const float*)d_in[2];
  const float* bias = (const float*)d_in[3];
  const float* pw   = (const float*)d_in[4];
  const float* pb   = (const float*)d_in[5];
  float* out = (float*)d_out;

  const size_t MB = 1ull << 20;
  const size_t FIXED = 4*MB /*partial*/ + 2*MB /*u_bf*/ + 2*MB /*pw_bf*/;

  if (ws_size >= FIXED + 4*MB) {
    float*  partial = (float*)d_ws;
    ushort* u_bf    = (ushort*)((char*)d_ws + 4*MB);
    ushort* pw_bf   = (ushort*)((char*)d_ws + 6*MB);
    char*   cbase   = (char*)d_ws + 8*MB;
    int cnb = (int)((ws_size - FIXED) / (4*MB));   // per-b: h_bf 2MB + lam_bf 2MB
    if (cnb > BATCH) cnb = BATCH;

    cvt_bf16<<<dim3(512), dim3(256), 0, stream>>>(uu, u_bf, 262144);
    cvt_bf16<<<dim3(512), dim3(256), 0, stream>>>(pw, pw_bf, 262144);

    for (int b0 = 0; b0 < BATCH; b0 += cnb){
      int nb = (BATCH - b0) < cnb ? (BATCH - b0) : cnb;
      ushort* h_bf   = (ushort*)cbase;
      ushort* lam_bf = (ushort*)(cbase + (size_t)nb*2*MB);
      cvt2_bf16<<<dim3(2048), dim3(256), 0, stream>>>(
          h   + ((size_t)b0 << 20), h_bf,
          lam + ((size_t)b0 << 20), lam_bf, nb*131072);
      fused_diag<<<dim3(nb*64), dim3(256), 0, stream>>>(h_bf, pw_bf, u_bf, lam_bf, pb, partial, b0);
    }
    bcast_out<<<dim3(512), dim3(256), 0, stream>>>(partial, bias, out);
  } else {
    emergency_fused<<<dim3(BATCH*D_), dim3(256), 0, stream>>>(h, lam, uu, bias, pw, pb, out);
  }
}

// Round 14
// 423.946 us; speedup vs baseline: 1.0872x; 1.0872x over previous
//
#include <hip/hip_runtime.h>
#include <hip/hip_bf16.h>

// B=64, D=1024, M=1024, DMODEL=1024, PRED_LEN=96
//   hp[b,i,f] = sum_c h[b,i,c]*pw[f,c] + pb[f]
//   P [b,i,f] = sum_m u[i,m]*lam[b,f,m]
//   diag[b,i] = sum_f hp[b,i,f]*P[b,i,f];  out[b,i,:] = diag[b,i] + bias[i]
//
// R12 restore (best measured: 428us total; fused 294us/937TF/0-conflict):
// cvt2(u,pw) + cvt2(h,lam) f32->bf16 -> ONE fused kernel per
// (b, i-tile, f-tile): hp-tile GEMM -> pack bf16+pb in regs -> P-tile GEMM
// (same counted-vmcnt dbuf core) -> in-register hadamard/rowsum -> 16
// partial strips -> fast 512-block strip-sum broadcast.
// NOTE (R13 lesson): the mid-phase lgkm0+barrier between frag reads and MFMA
// is load-bearing — removing it dropped MfmaUtil 42->34%. Do not "optimize"
// it away.

#define D_    1024
#define BATCH 64
#define PRED  96

typedef __attribute__((ext_vector_type(8))) short  bf16x8;
typedef __attribute__((ext_vector_type(8))) ushort ushort8;
typedef __attribute__((ext_vector_type(4))) float  f32x4;
typedef __attribute__((ext_vector_type(4))) ushort us4;

__device__ __forceinline__ ushort f2bf(float f){
  union { __hip_bfloat16 b; ushort u; } cv;
  cv.b = __float2bfloat16(f);
  return cv.u;
}
__device__ __forceinline__ float bf2f(ushort v){
  union { ushort u; __hip_bfloat16 b; } cv;
  cv.u = v;
  return __bfloat162float(cv.b);
}

// bijective XCD swizzle (m204 form)
__device__ __forceinline__ int xcd_swz(int orig, int nwg){
  int q = nwg >> 3, r = nwg & 7;
  int x = orig & 7, o = orig >> 3;
  return (x < r ? x*(q+1) : r*(q+1) + (x-r)*q) + o;
}

// async global->LDS, 16B per lane; LDS dest = wave-uniform base + lane*16
__device__ __forceinline__ void gload16(const ushort* g, ushort* l){
  __builtin_amdgcn_global_load_lds(
      (const __attribute__((address_space(1))) void*)g,
      (__attribute__((address_space(3))) void*)l, 16, 0, 0);
}

// ------- big f32 -> bf16 convert, two tensors in one pass -------
// nt loads (f32 never re-read); REGULAR stores (bf16 reused by GEMM -> L3).
__global__ __launch_bounds__(256) void cvt2_bf16(
    const float* __restrict__ inA, ushort* __restrict__ outA,
    const float* __restrict__ inB, ushort* __restrict__ outB, int n8each){
  int stride = (int)gridDim.x * 256;
  for (int i = (int)blockIdx.x*256 + (int)threadIdx.x; i < 2*n8each; i += stride){
    const f32x4* src; ushort* dst; int j;
    if (i < n8each){ src = (const f32x4*)inA; dst = outA; j = i; }
    else           { src = (const f32x4*)inB; dst = outB; j = i - n8each; }
    f32x4 a = __builtin_nontemporal_load(src + 2*(size_t)j);
    f32x4 b = __builtin_nontemporal_load(src + 2*(size_t)j + 1);
    ushort8 o;
    o[0]=f2bf(a.x); o[1]=f2bf(a.y); o[2]=f2bf(a.z); o[3]=f2bf(a.w);
    o[4]=f2bf(b.x); o[5]=f2bf(b.y); o[6]=f2bf(b.z); o[7]=f2bf(b.w);
    *(ushort8*)(dst + (size_t)j*8) = o;
  }
}

// Shared K-loop core (depth-2 counted pipeline), proven R3/R5/R12 (0 bank
// conflicts, 937 TF). LDS: sA/sB each 2 x 128x64 ushorts (dbuf).
// T2: LDS[r][chunk] = G[r][chunk ^ (r&7)] via pre-swizzled source; reads XOR back.
#define GEMM_CORE(Apan, Bpan, ACC)                                              \
  {                                                                             \
    _Pragma("unroll")                                                           \
    for (int q = 0; q < 4; ++q){                                                \
      int r0 = q*32 + wv*8;                                                     \
      gload16(Apan + (size_t)(r0 + srow)*D_ + scol, sA + r0*64);                \
      gload16(Bpan + (size_t)(r0 + srow)*D_ + scol, sB + r0*64);                \
    }                                                                           \
    _Pragma("unroll")                                                           \
    for (int q = 0; q < 4; ++q){                                                \
      int r0 = q*32 + wv*8;                                                     \
      gload16(Apan + 64 + (size_t)(r0 + srow)*D_ + scol, sA + 128*64 + r0*64);  \
      gload16(Bpan + 64 + (size_t)(r0 + srow)*D_ + scol, sB + 128*64 + r0*64);  \
    }                                                                           \
    for (int t = 0; t < 16; ++t){                                               \
      const int cur = t & 1;                                                    \
      ushort* sAc = sA + cur*(128*64);                                          \
      ushort* sBc = sB + cur*(128*64);                                          \
      if (t < 15) asm volatile("s_waitcnt vmcnt(8)" ::: "memory");              \
      else        asm volatile("s_waitcnt vmcnt(0)" ::: "memory");              \
      __builtin_amdgcn_s_barrier();                                             \
      bf16x8 af[2][4], bfr[2][4];                                               \
      _Pragma("unroll")                                                         \
      for (int kk = 0; kk < 2; ++kk){                                           \
        int cb = kk*4 + (lane >> 4);                                            \
        _Pragma("unroll")                                                       \
        for (int x = 0; x < 4; ++x){                                            \
          int ra = wr*64 + x*16 + (lane & 15);                                  \
          af[kk][x]  = *(const bf16x8*)(sAc + ra*64 + ((cb ^ (ra & 7)) << 3));  \
          int rb = wc*64 + x*16 + (lane & 15);                                  \
          bfr[kk][x] = *(const bf16x8*)(sBc + rb*64 + ((cb ^ (rb & 7)) << 3));  \
        }                                                                       \
      }                                                                         \
      asm volatile("s_waitcnt lgkmcnt(0)" ::: "memory");                        \
      __builtin_amdgcn_sched_barrier(0);                                        \
      __builtin_amdgcn_s_barrier();                                             \
      if (t < 14){                                                              \
        const ushort* An = Apan + (t+2)*64;                                     \
        const ushort* Bn = Bpan + (t+2)*64;                                     \
        _Pragma("unroll")                                                       \
        for (int q = 0; q < 4; ++q){                                            \
          int r0 = q*32 + wv*8;                                                 \
          gload16(An + (size_t)(r0 + srow)*D_ + scol, sAc + r0*64);             \
          gload16(Bn + (size_t)(r0 + srow)*D_ + scol, sBc + r0*64);             \
        }                                                                       \
      }                                                                         \
      __builtin_amdgcn_s_setprio(1);                                            \
      _Pragma("unroll")                                                         \
      for (int kk = 0; kk < 2; ++kk)                                            \
        _Pragma("unroll")                                                       \
        for (int x = 0; x < 4; ++x)                                             \
          _Pragma("unroll")                                                     \
          for (int y = 0; y < 4; ++y)                                           \
            ACC[x][y] = __builtin_amdgcn_mfma_f32_16x16x32_bf16(                \
                            af[kk][x], bfr[kk][y], ACC[x][y], 0, 0, 0);         \
      __builtin_amdgcn_s_setprio(0);                                            \
    }                                                                           \
  }

// ---------------- fused: hp-tile GEMM + P-tile GEMM + diag epilogue ----------------
__global__ __launch_bounds__(256, 2) void fused_diag(
    const ushort* __restrict__ hbf, const ushort* __restrict__ pwbf,
    const ushort* __restrict__ ubf, const ushort* __restrict__ lambf,
    const float* __restrict__ pb, float* __restrict__ partial, int b0)
{
  __shared__ ushort sA[2*128*64];
  __shared__ ushort sB[2*128*64];
  int bid = xcd_swz((int)blockIdx.x, (int)gridDim.x);
  int bl = bid >> 6;
  int t_ = bid & 63;
  int it = t_ >> 3, ft = t_ & 7;
  const ushort* ApanH = hbf  + ((size_t)bl << 20) + (size_t)(it*128) * D_;
  const ushort* BpanW = pwbf + (size_t)(ft*128) * D_;
  const ushort* ApanU = ubf  + (size_t)(it*128) * D_;
  const ushort* BpanL = lambf + ((size_t)bl << 20) + (size_t)(ft*128) * D_;
  int tid = threadIdx.x, lane = tid & 63, wv = tid >> 6;
  int wr = wv >> 1, wc = wv & 1;
  int srow = lane >> 3;
  int scol = (((lane & 7) ^ srow) << 3);     // T2 pre-swizzled source chunk

  f32x4 acc[4][4];
  #pragma unroll
  for (int x = 0; x < 4; ++x)
    #pragma unroll
    for (int y = 0; y < 4; ++y) acc[x][y] = (f32x4){0.f,0.f,0.f,0.f};

  // ---- loop 1: hp-tile = h @ pw^T ----
  GEMM_CORE(ApanH, BpanW, acc)

  // pack hp (+pb) to bf16 in registers; reset acc for loop 2
  us4 hp_pk[4][4];
  #pragma unroll
  for (int y = 0; y < 4; ++y){
    int gk = ft*128 + wc*64 + y*16 + (lane & 15);
    float pbv = pb[gk];
    #pragma unroll
    for (int x = 0; x < 4; ++x){
      us4 p;
      p.x = f2bf(acc[x][y][0] + pbv); p.y = f2bf(acc[x][y][1] + pbv);
      p.z = f2bf(acc[x][y][2] + pbv); p.w = f2bf(acc[x][y][3] + pbv);
      hp_pk[x][y] = p;
      acc[x][y] = (f32x4){0.f,0.f,0.f,0.f};
    }
  }

  // ---- loop 2: P-tile = u @ lam^T ----
  GEMM_CORE(ApanU, BpanL, acc)

  // ---- epilogue: ps = rowsum over this wave's 64 cols of hp .* P ----
  f32x4 ps[4];
  #pragma unroll
  for (int x = 0; x < 4; ++x) ps[x] = (f32x4){0.f,0.f,0.f,0.f};
  #pragma unroll
  for (int y = 0; y < 4; ++y)
    #pragma unroll
    for (int x = 0; x < 4; ++x){
      ps[x][0] += bf2f(hp_pk[x][y].x) * acc[x][y][0];
      ps[x][1] += bf2f(hp_pk[x][y].y) * acc[x][y][1];
      ps[x][2] += bf2f(hp_pk[x][y].z) * acc[x][y][2];
      ps[x][3] += bf2f(hp_pk[x][y].w) * acc[x][y][3];
    }
  // butterfly over the 16 cols (lane bits 0..3); preserves row group (lane>>4)
  #pragma unroll
  for (int x = 0; x < 4; ++x)
    #pragma unroll
    for (int r = 0; r < 4; ++r){
      float v = ps[x][r];
      #pragma unroll
      for (int mm = 1; mm < 16; mm <<= 1) v += __shfl_xor(v, mm, 64);
      ps[x][r] = v;
    }
  // deterministic partial strips: strip = ft*2 + wc  (16 strips)
  if ((lane & 15) == 0){
    int strip = ft*2 + wc;
    float* pdst = partial + (size_t)strip*(BATCH*D_) + (size_t)(b0 + bl)*D_;
    #pragma unroll
    for (int x = 0; x < 4; ++x){
      int gi0 = it*128 + wr*64 + x*16 + (lane >> 4)*4;
      #pragma unroll
      for (int r = 0; r < 4; ++r) pdst[gi0 + r] = ps[x][r];
    }
  }
}

// ------- K3: diag = sum(strips) + bias; broadcast to 96 (fast 512-block) -------
__global__ __launch_bounds__(256) void bcast_out(
    const float* __restrict__ partial, const float* __restrict__ bias,
    float* __restrict__ out)
{
  int tid = threadIdx.x;
  int row = (int)blockIdx.x*128 + (tid >> 1);   // 512 blocks x 128 rows
  int half = tid & 1;
  int i = row & (D_-1);
  float s = bias[i];
  #pragma unroll
  for (int st = 0; st < 16; ++st) s += partial[(size_t)st*(BATCH*D_) + row];
  f32x4 v = {s, s, s, s};
  float* dst = out + (size_t)row*PRED + half*48;
  #pragma unroll
  for (int j = 0; j < 12; ++j) ((f32x4*)dst)[j] = v;
}

// ---------------- emergency path: no workspace needed (slow, correct) ----------------
__global__ __launch_bounds__(256) void emergency_fused(
    const float* __restrict__ h, const float* __restrict__ lam,
    const float* __restrict__ uu, const float* __restrict__ bias,
    const float* __restrict__ pw, const float* __restrict__ pb,
    float* __restrict__ out)
{
  int b = blockIdx.x >> 10;
  int i = blockIdx.x & (D_-1);
  __shared__ float hps[D_];
  __shared__ float red[4];
  __shared__ float dv;
  const float* hrow = h + ((size_t)b << 20) + (size_t)i*D_;
  for (int f = threadIdx.x; f < D_; f += 256){
    const float* pwr = pw + (size_t)f*D_;
    float s = pb[f];
    for (int c = 0; c < D_; ++c) s += hrow[c]*pwr[c];
    hps[f] = s;
  }
  __syncthreads();
  const float* urow = uu + (size_t)i*D_;
  float d = 0.f;
  for (int f = threadIdx.x; f < D_; f += 256){
    const float* lr = lam + ((size_t)b << 20) + (size_t)f*D_;
    float p = 0.f;
    for (int m = 0; m < D_; ++m) p += lr[m]*urow[m];
    d += hps[f]*p;
  }
  for (int off = 32; off; off >>= 1) d += __shfl_down(d, off, 64);
  if ((threadIdx.x & 63) == 0) red[threadIdx.x >> 6] = d;
  __syncthreads();
  if (threadIdx.x == 0) dv = red[0]+red[1]+red[2]+red[3] + bias[i];
  __syncthreads();
  if (threadIdx.x < PRED) out[(size_t)blockIdx.x*PRED + threadIdx.x] = dv;
}

extern "C" void kernel_launch(void* const* d_in, const int* in_sizes, int n_in,
                              void* d_out, int out_size, void* d_ws, size_t ws_size,
                              hipStream_t stream) {
  const float* h    = (const float*)d_in[0];
  const float* lam  = (const float*)d_in[1];
  const float* uu   = (const float*)d_in[2];
  const float* bias = (const float*)d_in[3];
  const float* pw   = (const float*)d_in[4];
  const float* pb   = (const float*)d_in[5];
  float* out = (float*)d_out;

  const size_t MB = 1ull << 20;
  const size_t FIXED = 4*MB /*partial*/ + 2*MB /*u_bf*/ + 2*MB /*pw_bf*/;

  if (ws_size >= FIXED + 4*MB) {
    float*  partial = (float*)d_ws;
    ushort* u_bf    = (ushort*)((char*)d_ws + 4*MB);
    ushort* pw_bf   = (ushort*)((char*)d_ws + 6*MB);
    char*   cbase   = (char*)d_ws + 8*MB;
    int cnb = (int)((ws_size - FIXED) / (4*MB));   // per-b: h_bf 2MB + lam_bf 2MB
    if (cnb > BATCH) cnb = BATCH;

    // u and pw (2 MB each) in one merged convert launch
    cvt2_bf16<<<dim3(512), dim3(256), 0, stream>>>(uu, u_bf, pw, pw_bf, 131072);

    for (int b0 = 0; b0 < BATCH; b0 += cnb){
      int nb = (BATCH - b0) < cnb ? (BATCH - b0) : cnb;
      ushort* h_bf   = (ushort*)cbase;
      ushort* lam_bf = (ushort*)(cbase + (size_t)nb*2*MB);
      cvt2_bf16<<<dim3(2048), dim3(256), 0, stream>>>(
          h   + ((size_t)b0 << 20), h_bf,
          lam + ((size_t)b0 << 20), lam_bf, nb*131072);
      fused_diag<<<dim3(nb*64), dim3(256), 0, stream>>>(h_bf, pw_bf, u_bf, lam_bf, pb, partial, b0);
    }
    bcast_out<<<dim3(512), dim3(256), 0, stream>>>(partial, bias, out);
  } else {
    emergency_fused<<<dim3(BATCH*D_), dim3(256), 0, stream>>>(h, lam, uu, bias, pw, pb, out);
  }
}